// Round 1
// baseline (379.920 us; speedup 1.0000x reference)
//
#include <hip/hip_runtime.h>
#include <math.h>

#define B_   8
#define S_   1024
#define HDIM 768
#define FDIM 32
#define KDIM 800
#define D_   64

constexpr float NEGV = -1000000000000.0f;

// ---------------------------------------------------------------------------
// k1: fused concat + GEMM (800 -> 146 cols) + bias + RoPE + scale-folding.
// Block: 256 threads, 32 rows. Cols 0..127 = W1 out (q/k interleaved),
// cols 128..145 = W2 out (bias). W read direct from global (L1/L2 resident).
// ---------------------------------------------------------------------------
__global__ __launch_bounds__(256) void k1_proj(
    const float* __restrict__ lhs, const float* __restrict__ hf,
    const float* __restrict__ W1,  const float* __restrict__ b1,
    const float* __restrict__ W2,  const float* __restrict__ b2,
    float* __restrict__ qw, float* __restrict__ kw, float* __restrict__ bias_t)
{
    __shared__ float sh_h[32][33];     // [row][kk], +1 pad
    __shared__ float sh_out[32][148];  // [row][col], 146 used

    const int tid = threadIdx.x;
    const int m0  = blockIdx.x * 32;
    const int tc  = tid & 15;
    const int tr  = tid >> 4;

    float acc[2][10];
#pragma unroll
    for (int i = 0; i < 2; ++i)
#pragma unroll
        for (int j = 0; j < 10; ++j) acc[i][j] = 0.0f;

    for (int chunk = 0; chunk < KDIM / 32; ++chunk) {
        const int k0 = chunk * 32;
        {   // stage 32x32 h tile (concat view)
            const int row  = tid >> 3;
            const int kk   = (tid & 7) * 4;
            const int gk   = k0 + kk;
            const int grow = m0 + row;
            float4 v;
            if (gk < HDIM) v = *(const float4*)(lhs + (size_t)grow * HDIM + gk);
            else           v = *(const float4*)(hf  + (size_t)grow * FDIM + (gk - HDIM));
            sh_h[row][kk + 0] = v.x; sh_h[row][kk + 1] = v.y;
            sh_h[row][kk + 2] = v.z; sh_h[row][kk + 3] = v.w;
        }
        __syncthreads();
#pragma unroll 4
        for (int kk = 0; kk < 32; ++kk) {
            const int k = k0 + kk;
            const float a0 = sh_h[tr * 2 + 0][kk];
            const float a1 = sh_h[tr * 2 + 1][kk];
            const float* w1row = W1 + (size_t)k * 128;
            const float* w2row = W2 + (size_t)k * 18;
#pragma unroll
            for (int jj = 0; jj < 8; ++jj) {
                const float w = w1row[tc + jj * 16];
                acc[0][jj] = fmaf(a0, w, acc[0][jj]);
                acc[1][jj] = fmaf(a1, w, acc[1][jj]);
            }
            {
                const float w = w2row[tc];
                acc[0][8] = fmaf(a0, w, acc[0][8]);
                acc[1][8] = fmaf(a1, w, acc[1][8]);
            }
            if (tc < 2) {
                const float w = w2row[16 + tc];
                acc[0][9] = fmaf(a0, w, acc[0][9]);
                acc[1][9] = fmaf(a1, w, acc[1][9]);
            }
        }
        __syncthreads();
    }

    // add biases, park in LDS for the RoPE re-partition
#pragma unroll
    for (int i = 0; i < 2; ++i) {
        const int r = tr * 2 + i;
#pragma unroll
        for (int jj = 0; jj < 8; ++jj)
            sh_out[r][tc + jj * 16] = acc[i][jj] + b1[tc + jj * 16];
        sh_out[r][128 + tc] = acc[i][8] + b2[tc];
        if (tc < 2) sh_out[r][144 + tc] = acc[i][9] + b2[16 + tc];
    }
    __syncthreads();

    const int bidx = m0 >> 10;   // batch (32 | 1024, so uniform per block)
    const int s0   = m0 & 1023;

    // RoPE: pair i couples out-cols {4i,4i+2} (q) and {4i+1,4i+3} (k).
    // Fold 1/sqrt(64)=0.125 into qw.
#pragma unroll
    for (int step = 0; step < 4; ++step) {
        const int item = tid + step * 256;   // 0..1023 = 32 rows x 32 pairs
        const int row  = item >> 5;
        const int i    = item & 31;
        const float pos  = (float)(s0 + row);
        const float freq = powf(10000.0f, -(float)i * (1.0f / 32.0f));
        float sv, cv;
        sincosf(pos * freq, &sv, &cv);

        float x0 = sh_out[row][4 * i + 0];
        float x1 = sh_out[row][4 * i + 2];
        float2 q2 = make_float2((x0 * cv - x1 * sv) * 0.125f,
                                (x1 * cv + x0 * sv) * 0.125f);
        *(float2*)(qw + (size_t)(m0 + row) * D_ + 2 * i) = q2;

        x0 = sh_out[row][4 * i + 1];
        x1 = sh_out[row][4 * i + 3];
        float2 k2 = make_float2(x0 * cv - x1 * sv,
                                x1 * cv + x0 * sv);
        *(float2*)(kw + (size_t)(m0 + row) * D_ + 2 * i) = k2;
    }

    // bias (already /2-folded) stored transposed: bias_t[b][c][s]
    for (int idx = tid; idx < 32 * 18; idx += 256) {
        const int row = idx / 18;
        const int c   = idx - row * 18;
        bias_t[(((size_t)(bidx * 18 + c)) << 10) + s0 + row] =
            sh_out[row][128 + c] * 0.5f;
    }
}

// ---------------------------------------------------------------------------
// k2: per (b, 64x64 m/n tile): qk = qw.kw (k-major LDS, float4 reads),
// then 9 write passes with bias broadcast + mask + tril.
// ---------------------------------------------------------------------------
__global__ __launch_bounds__(256) void k2_logits(
    const float* __restrict__ qw, const float* __restrict__ kw,
    const float* __restrict__ bias_t, const int* __restrict__ mask,
    float* __restrict__ out)
{
    __shared__ float qs [64][64];   // [k][m]
    __shared__ float ks2[64][64];   // [k][n]
    __shared__ float bn[18][64];    // bias over n
    __shared__ float bm[18][64];    // bias over m
    __shared__ float mqf[64], mkf[64];

    const int tid = threadIdx.x;
    const int bid = blockIdx.x;
    const int b   = bid >> 8;
    const int rem = bid & 255;
    const int m0  = (rem >> 4) << 6;
    const int n0  = (rem & 15) << 6;

    {   // stage qw/kw transposed into LDS (conflict-free scalar writes: 2-way)
        const int row = tid & 63;
        const int kq  = (tid >> 6) * 16;
        const float* qsrc = qw + ((size_t)(b * S_) + m0 + row) * D_ + kq;
        const float* ksrc = kw + ((size_t)(b * S_) + n0 + row) * D_ + kq;
#pragma unroll
        for (int u = 0; u < 4; ++u) {
            float4 v = *(const float4*)(qsrc + u * 4);
            qs [kq + u * 4 + 0][row] = v.x; qs [kq + u * 4 + 1][row] = v.y;
            qs [kq + u * 4 + 2][row] = v.z; qs [kq + u * 4 + 3][row] = v.w;
            float4 w = *(const float4*)(ksrc + u * 4);
            ks2[kq + u * 4 + 0][row] = w.x; ks2[kq + u * 4 + 1][row] = w.y;
            ks2[kq + u * 4 + 2][row] = w.z; ks2[kq + u * 4 + 3][row] = w.w;
        }
    }
    for (int idx = tid; idx < 18 * 64; idx += 256) {
        const int c = idx >> 6;
        const int x = idx & 63;
        bn[c][x] = bias_t[(((size_t)(b * 18 + c)) << 10) + n0 + x];
        bm[c][x] = bias_t[(((size_t)(b * 18 + c)) << 10) + m0 + x];
    }
    if (tid < 64)        mqf[tid]      = (float)mask[b * S_ + m0 + tid];
    else if (tid < 128)  mkf[tid - 64] = (float)mask[b * S_ + n0 + (tid - 64)];
    __syncthreads();

    const int tr = tid >> 4;   // 0..15 -> 4 m rows
    const int tc = tid & 15;   // 0..15 -> 4 n cols

    float acc[4][4];
#pragma unroll
    for (int i = 0; i < 4; ++i)
#pragma unroll
        for (int j = 0; j < 4; ++j) acc[i][j] = 0.0f;

#pragma unroll 4
    for (int k = 0; k < 64; ++k) {
        const float4 a  = *(const float4*)&qs [k][tr * 4];
        const float4 bv = *(const float4*)&ks2[k][tc * 4];
        const float av[4]  = {a.x,  a.y,  a.z,  a.w};
        const float bvv[4] = {bv.x, bv.y, bv.z, bv.w};
#pragma unroll
        for (int i = 0; i < 4; ++i)
#pragma unroll
            for (int j = 0; j < 4; ++j)
                acc[i][j] = fmaf(av[i], bvv[j], acc[i][j]);
    }

    // epilogue: 9 t-slices, float4 coalesced stores
#pragma unroll
    for (int t = 0; t < 9; ++t) {
        float bnv[4], vkk[4];
#pragma unroll
        for (int j = 0; j < 4; ++j) {
            bnv[j] = bn[2 * t][tc * 4 + j];
            vkk[j] = mkf[tc * 4 + j];
        }
#pragma unroll
        for (int i = 0; i < 4; ++i) {
            const int mg  = m0 + tr * 4 + i;
            const float bmv = bm[2 * t + 1][tr * 4 + i];
            const float vq  = mqf[tr * 4 + i];
            float vals[4];
#pragma unroll
            for (int j = 0; j < 4; ++j) {
                const int ng = n0 + tc * 4 + j;
                float v = acc[i][j] + bnv[j] + bmv;
                v = v * vq     + NEGV * (1.0f - vq);
                v = v * vkk[j] + NEGV * (1.0f - vkk[j]);
                if (mg > ng) v += NEGV;
                vals[j] = v;
            }
            const size_t base =
                (((size_t)(b * 9 + t)) * S_ + (size_t)mg) * S_ + n0 + tc * 4;
            *(float4*)(out + base) = make_float4(vals[0], vals[1], vals[2], vals[3]);
        }
    }
}

extern "C" void kernel_launch(void* const* d_in, const int* in_sizes, int n_in,
                              void* d_out, int out_size, void* d_ws, size_t ws_size,
                              hipStream_t stream) {
    const float* lhs  = (const float*)d_in[0];
    const float* hf   = (const float*)d_in[1];
    const int*   mask = (const int*)  d_in[2];
    const float* W1   = (const float*)d_in[3];
    const float* b1   = (const float*)d_in[4];
    const float* W2   = (const float*)d_in[5];
    const float* b2   = (const float*)d_in[6];
    float* out = (float*)d_out;

    float* wsf    = (float*)d_ws;
    float* qw     = wsf;                              // [8192][64]
    float* kw     = wsf + (size_t)B_ * S_ * D_;       // [8192][64]
    float* bias_t = wsf + (size_t)2 * B_ * S_ * D_;   // [8][18][1024]

    k1_proj<<<(B_ * S_) / 32, 256, 0, stream>>>(lhs, hf, W1, b1, W2, b2,
                                                qw, kw, bias_t);
    k2_logits<<<B_ * 16 * 16, 256, 0, stream>>>(qw, kw, bias_t, mask, out);
}

// Round 2
// 175.248 us; speedup vs baseline: 2.1679x; 2.1679x over previous
//
#include <hip/hip_runtime.h>
#include <math.h>

#define B_   8
#define S_   1024
#define HDIM 768
#define FDIM 32
#define KDIM 800
#define D_   64

constexpr float NEGV = -1000000000000.0f;

// ---------------------------------------------------------------------------
// k1: h @ W1 (800 -> 128) + b1 + RoPE, scale 0.125 folded into qw.
// Block: 32 rows x 128 cols, 256 threads (4 waves). Thread tile 4x4.
// LDS double-buffered K-chunks of 32; h staged transposed so RoPE pairs
// (cols 4i,4i+2 | 4i+1,4i+3) are thread-local.
// ---------------------------------------------------------------------------
__global__ __launch_bounds__(256) void k1_proj(
    const float* __restrict__ lhs, const float* __restrict__ hf,
    const float* __restrict__ W1,  const float* __restrict__ b1,
    float* __restrict__ qw, float* __restrict__ kw)
{
    __shared__ float sh_hT[2][32][36];   // [buf][kk][row], 36 keeps 16B align
    __shared__ float sh_w [2][32][128];  // [buf][kk][col]

    const int tid = threadIdx.x;
    const int m0  = blockIdx.x << 5;
    const int tr4 = ((tid >> 5) & 7) << 2;  // row offset 0..28
    const int tc  = tid & 31;               // col4 group
    const int tc4 = tc << 2;

    // staging indices
    const int srow = tid >> 3;           // 0..31
    const int skc4 = (tid & 7) << 2;     // 0..28

    float acc[4][4];
#pragma unroll
    for (int i = 0; i < 4; ++i)
#pragma unroll
        for (int j = 0; j < 4; ++j) acc[i][j] = 0.0f;

    float4 rh;        // h prefetch reg
    float4 rw[4];     // W prefetch regs

    auto load_chunk = [&](int c) {
        const int k0 = c << 5;
        const float* hsrc = (k0 < HDIM)
            ? lhs + (size_t)(m0 + srow) * HDIM + k0 + skc4
            : hf  + (size_t)(m0 + srow) * FDIM + (k0 - HDIM) + skc4;
        rh = *(const float4*)hsrc;
#pragma unroll
        for (int u = 0; u < 4; ++u) {
            const int flat = tid + (u << 8);
            const int kk = flat >> 5;
            const int c4 = (flat & 31) << 2;
            rw[u] = *(const float4*)(W1 + (size_t)(k0 + kk) * 128 + c4);
        }
    };
    auto commit_chunk = [&](int buf) {
        sh_hT[buf][skc4 + 0][srow] = rh.x;
        sh_hT[buf][skc4 + 1][srow] = rh.y;
        sh_hT[buf][skc4 + 2][srow] = rh.z;
        sh_hT[buf][skc4 + 3][srow] = rh.w;
#pragma unroll
        for (int u = 0; u < 4; ++u) {
            const int flat = tid + (u << 8);
            const int kk = flat >> 5;
            const int c4 = (flat & 31) << 2;
            *(float4*)&sh_w[buf][kk][c4] = rw[u];
        }
    };

    load_chunk(0);
    commit_chunk(0);
    __syncthreads();

    for (int c = 0; c < 25; ++c) {
        if (c < 24) load_chunk(c + 1);     // global->reg, in flight over compute
        const int buf = c & 1;
#pragma unroll
        for (int kk = 0; kk < 32; ++kk) {
            const float4 hv = *(const float4*)&sh_hT[buf][kk][tr4];
            const float4 wv = *(const float4*)&sh_w[buf][kk][tc4];
            const float h4[4] = {hv.x, hv.y, hv.z, hv.w};
            const float w4[4] = {wv.x, wv.y, wv.z, wv.w};
#pragma unroll
            for (int i = 0; i < 4; ++i)
#pragma unroll
                for (int j = 0; j < 4; ++j)
                    acc[i][j] = fmaf(h4[i], w4[j], acc[i][j]);
        }
        __syncthreads();                    // reads of other buffer done
        if (c < 24) {
            commit_chunk((c + 1) & 1);      // vmcnt wait lands here, post-compute
            __syncthreads();
        }
    }

    // epilogue: +b1, RoPE, fold 0.125 into qw
    const float4 b1v = *(const float4*)&b1[tc4];
    const float bb[4] = {b1v.x, b1v.y, b1v.z, b1v.w};
    const float freq = powf(10000.0f, -(float)tc * (1.0f / 32.0f));
#pragma unroll
    for (int i = 0; i < 4; ++i) {
        const int grow = m0 + tr4 + i;
        const float pos = (float)(grow & (S_ - 1));
        float sv, cv;
        sincosf(pos * freq, &sv, &cv);
        const float q0 = acc[i][0] + bb[0];
        const float k0 = acc[i][1] + bb[1];
        const float q1 = acc[i][2] + bb[2];
        const float k1 = acc[i][3] + bb[3];
        *(float2*)(qw + (size_t)grow * D_ + 2 * tc) =
            make_float2((q0 * cv - q1 * sv) * 0.125f,
                        (q1 * cv + q0 * sv) * 0.125f);
        *(float2*)(kw + (size_t)grow * D_ + 2 * tc) =
            make_float2(k0 * cv - k1 * sv,
                        k1 * cv + k0 * sv);
    }
}

// ---------------------------------------------------------------------------
// k1b: bias = (h @ W2 + b2) * 0.5, stored transposed bias_t[b][c][s].
// Block: 64 rows, 256 threads = 4 waves, K split {7,6,6,6} chunks of 32.
// W2 rows are wave-uniform -> scalar loads; h staged transposed in LDS.
// ---------------------------------------------------------------------------
__global__ __launch_bounds__(256) void k1b_bias(
    const float* __restrict__ lhs, const float* __restrict__ hf,
    const float* __restrict__ W2,  const float* __restrict__ b2,
    float* __restrict__ bias_t)
{
    __shared__ float sh_hT[4][32][65];   // per-wave [kk][row]
    __shared__ float red[4][64][19];

    const int tid  = threadIdx.x;
    const int w    = tid >> 6;
    const int lane = tid & 63;
    const int r0   = blockIdx.x << 6;

    const int c0 = (w == 0) ? 0 : 6 * w + 1;   // {0,7,13,19}
    const int c1 = 6 * w + 7;                  // {7,13,19,25}

    float acc[18];
#pragma unroll
    for (int j = 0; j < 18; ++j) acc[j] = 0.0f;

    for (int c = c0; c < c1; ++c) {
        const int k0 = c << 5;
        // stage 64 rows x 32 k transposed (this wave only; no barrier needed)
#pragma unroll
        for (int s = 0; s < 8; ++s) {
            const int flat4 = lane + (s << 6);
            const int row   = flat4 >> 3;
            const int kc4   = (flat4 & 7) << 2;
            const float* src = (k0 < HDIM)
                ? lhs + (size_t)(r0 + row) * HDIM + k0 + kc4
                : hf  + (size_t)(r0 + row) * FDIM + (k0 - HDIM) + kc4;
            const float4 v = *(const float4*)src;
            sh_hT[w][kc4 + 0][row] = v.x;
            sh_hT[w][kc4 + 1][row] = v.y;
            sh_hT[w][kc4 + 2][row] = v.z;
            sh_hT[w][kc4 + 3][row] = v.w;
        }
#pragma unroll 4
        for (int kk = 0; kk < 32; ++kk) {
            const float hv = sh_hT[w][kk][lane];
            const float* w2r = W2 + (size_t)(k0 + kk) * 18;   // wave-uniform
#pragma unroll
            for (int j = 0; j < 18; ++j)
                acc[j] = fmaf(hv, w2r[j], acc[j]);
        }
    }

#pragma unroll
    for (int j = 0; j < 18; ++j) red[w][lane][j] = acc[j];
    __syncthreads();

    if (w == 0) {
        const int b = r0 >> 10;
        const int s = r0 & (S_ - 1);
#pragma unroll
        for (int j = 0; j < 18; ++j) {
            float v = red[0][lane][j] + red[1][lane][j] +
                      red[2][lane][j] + red[3][lane][j];
            v = (v + b2[j]) * 0.5f;
            bias_t[(((size_t)(b * 18 + j)) << 10) + s + lane] = v;
        }
    }
}

// ---------------------------------------------------------------------------
// k2: per (b, 64x64 m/n tile): qk = qw.kw (k-major LDS, float4 reads),
// then 9 write passes with bias broadcast + mask + tril.  (unchanged)
// ---------------------------------------------------------------------------
__global__ __launch_bounds__(256) void k2_logits(
    const float* __restrict__ qw, const float* __restrict__ kw,
    const float* __restrict__ bias_t, const int* __restrict__ mask,
    float* __restrict__ out)
{
    __shared__ float qs [64][64];   // [k][m]
    __shared__ float ks2[64][64];   // [k][n]
    __shared__ float bn[18][64];
    __shared__ float bm[18][64];
    __shared__ float mqf[64], mkf[64];

    const int tid = threadIdx.x;
    const int bid = blockIdx.x;
    const int b   = bid >> 8;
    const int rem = bid & 255;
    const int m0  = (rem >> 4) << 6;
    const int n0  = (rem & 15) << 6;

    {
        const int row = tid & 63;
        const int kq  = (tid >> 6) * 16;
        const float* qsrc = qw + ((size_t)(b * S_) + m0 + row) * D_ + kq;
        const float* ksrc = kw + ((size_t)(b * S_) + n0 + row) * D_ + kq;
#pragma unroll
        for (int u = 0; u < 4; ++u) {
            float4 v = *(const float4*)(qsrc + u * 4);
            qs [kq + u * 4 + 0][row] = v.x; qs [kq + u * 4 + 1][row] = v.y;
            qs [kq + u * 4 + 2][row] = v.z; qs [kq + u * 4 + 3][row] = v.w;
            float4 w = *(const float4*)(ksrc + u * 4);
            ks2[kq + u * 4 + 0][row] = w.x; ks2[kq + u * 4 + 1][row] = w.y;
            ks2[kq + u * 4 + 2][row] = w.z; ks2[kq + u * 4 + 3][row] = w.w;
        }
    }
    for (int idx = tid; idx < 18 * 64; idx += 256) {
        const int c = idx >> 6;
        const int x = idx & 63;
        bn[c][x] = bias_t[(((size_t)(b * 18 + c)) << 10) + n0 + x];
        bm[c][x] = bias_t[(((size_t)(b * 18 + c)) << 10) + m0 + x];
    }
    if (tid < 64)        mqf[tid]      = (float)mask[b * S_ + m0 + tid];
    else if (tid < 128)  mkf[tid - 64] = (float)mask[b * S_ + n0 + (tid - 64)];
    __syncthreads();

    const int tr = tid >> 4;
    const int tc = tid & 15;

    float acc[4][4];
#pragma unroll
    for (int i = 0; i < 4; ++i)
#pragma unroll
        for (int j = 0; j < 4; ++j) acc[i][j] = 0.0f;

#pragma unroll 4
    for (int k = 0; k < 64; ++k) {
        const float4 a  = *(const float4*)&qs [k][tr * 4];
        const float4 bv = *(const float4*)&ks2[k][tc * 4];
        const float av[4]  = {a.x,  a.y,  a.z,  a.w};
        const float bvv[4] = {bv.x, bv.y, bv.z, bv.w};
#pragma unroll
        for (int i = 0; i < 4; ++i)
#pragma unroll
            for (int j = 0; j < 4; ++j)
                acc[i][j] = fmaf(av[i], bvv[j], acc[i][j]);
    }

#pragma unroll
    for (int t = 0; t < 9; ++t) {
        float bnv[4], vkk[4];
#pragma unroll
        for (int j = 0; j < 4; ++j) {
            bnv[j] = bn[2 * t][tc * 4 + j];
            vkk[j] = mkf[tc * 4 + j];
        }
#pragma unroll
        for (int i = 0; i < 4; ++i) {
            const int mg  = m0 + tr * 4 + i;
            const float bmv = bm[2 * t + 1][tr * 4 + i];
            const float vq  = mqf[tr * 4 + i];
            float vals[4];
#pragma unroll
            for (int j = 0; j < 4; ++j) {
                const int ng = n0 + tc * 4 + j;
                float v = acc[i][j] + bnv[j] + bmv;
                v = v * vq     + NEGV * (1.0f - vq);
                v = v * vkk[j] + NEGV * (1.0f - vkk[j]);
                if (mg > ng) v += NEGV;
                vals[j] = v;
            }
            const size_t base =
                (((size_t)(b * 9 + t)) * S_ + (size_t)mg) * S_ + n0 + tc * 4;
            *(float4*)(out + base) = make_float4(vals[0], vals[1], vals[2], vals[3]);
        }
    }
}

extern "C" void kernel_launch(void* const* d_in, const int* in_sizes, int n_in,
                              void* d_out, int out_size, void* d_ws, size_t ws_size,
                              hipStream_t stream) {
    const float* lhs  = (const float*)d_in[0];
    const float* hf   = (const float*)d_in[1];
    const int*   mask = (const int*)  d_in[2];
    const float* W1   = (const float*)d_in[3];
    const float* b1   = (const float*)d_in[4];
    const float* W2   = (const float*)d_in[5];
    const float* b2   = (const float*)d_in[6];
    float* out = (float*)d_out;

    float* wsf    = (float*)d_ws;
    float* qw     = wsf;                              // [8192][64]
    float* kw     = wsf + (size_t)B_ * S_ * D_;       // [8192][64]
    float* bias_t = wsf + (size_t)2 * B_ * S_ * D_;   // [8][18][1024]

    k1_proj<<<(B_ * S_) / 32, 256, 0, stream>>>(lhs, hf, W1, b1, qw, kw);
    k1b_bias<<<(B_ * S_) / 64, 256, 0, stream>>>(lhs, hf, W2, b2, bias_t);
    k2_logits<<<B_ * 16 * 16, 256, 0, stream>>>(qw, kw, bias_t, mask, out);
}

// Round 3
// 163.154 us; speedup vs baseline: 2.3286x; 1.0741x over previous
//
#include <hip/hip_runtime.h>
#include <math.h>

#define B_   8
#define S_   1024
#define HDIM 768
#define FDIM 32
#define KDIM 800
#define D_   64

constexpr float NEGV = -1000000000000.0f;

typedef __attribute__((ext_vector_type(8))) short short8;
typedef __attribute__((ext_vector_type(4))) float f32x4;

static __device__ __forceinline__ unsigned short f2bf(float f) {
    unsigned int x = __float_as_uint(f);
    unsigned int r = (x + 0x7fffu + ((x >> 16) & 1u)) >> 16;   // RNE
    return (unsigned short)r;
}

// ---------------------------------------------------------------------------
// k1: h @ W1 (800 -> 128) + b1 + RoPE -> qw/kw in bf16 [m][64].
// 256 threads, 32 rows x 128 cols, 4x4 thread tile, single-barrier dbuf.
// ---------------------------------------------------------------------------
__global__ __launch_bounds__(256) void k1_proj(
    const float* __restrict__ lhs, const float* __restrict__ hf,
    const float* __restrict__ W1,  const float* __restrict__ b1,
    unsigned short* __restrict__ qw, unsigned short* __restrict__ kw)
{
    __shared__ float sh_hT[2][32][36];
    __shared__ float sh_w [2][32][128];

    const int tid = threadIdx.x;
    const int m0  = blockIdx.x << 5;
    const int tr4 = ((tid >> 5) & 7) << 2;
    const int tc  = tid & 31;
    const int tc4 = tc << 2;
    const int srow = tid >> 3;
    const int skc4 = (tid & 7) << 2;

    float acc[4][4];
#pragma unroll
    for (int i = 0; i < 4; ++i)
#pragma unroll
        for (int j = 0; j < 4; ++j) acc[i][j] = 0.0f;

    float4 rh;
    float4 rw[4];

    auto load_chunk = [&](int c) {
        const int k0 = c << 5;
        const float* hsrc = (k0 < HDIM)
            ? lhs + (size_t)(m0 + srow) * HDIM + k0 + skc4
            : hf  + (size_t)(m0 + srow) * FDIM + (k0 - HDIM) + skc4;
        rh = *(const float4*)hsrc;
#pragma unroll
        for (int u = 0; u < 4; ++u) {
            const int flat = tid + (u << 8);
            const int kk = flat >> 5;
            const int c4 = (flat & 31) << 2;
            rw[u] = *(const float4*)(W1 + (size_t)(k0 + kk) * 128 + c4);
        }
    };
    auto commit_chunk = [&](int buf) {
        sh_hT[buf][skc4 + 0][srow] = rh.x;
        sh_hT[buf][skc4 + 1][srow] = rh.y;
        sh_hT[buf][skc4 + 2][srow] = rh.z;
        sh_hT[buf][skc4 + 3][srow] = rh.w;
#pragma unroll
        for (int u = 0; u < 4; ++u) {
            const int flat = tid + (u << 8);
            const int kk = flat >> 5;
            const int c4 = (flat & 31) << 2;
            *(float4*)&sh_w[buf][kk][c4] = rw[u];
        }
    };

    load_chunk(0);
    commit_chunk(0);

    for (int c = 0; c < 25; ++c) {
        __syncthreads();                 // buf[c&1] committed & prior reads done
        if (c < 24) load_chunk(c + 1);   // issue next-chunk global loads
        const int buf = c & 1;
#pragma unroll
        for (int kk = 0; kk < 32; ++kk) {
            const float4 hv = *(const float4*)&sh_hT[buf][kk][tr4];
            const float4 wv = *(const float4*)&sh_w[buf][kk][tc4];
            const float h4[4] = {hv.x, hv.y, hv.z, hv.w};
            const float w4[4] = {wv.x, wv.y, wv.z, wv.w};
#pragma unroll
            for (int i = 0; i < 4; ++i)
#pragma unroll
                for (int j = 0; j < 4; ++j)
                    acc[i][j] = fmaf(h4[i], w4[j], acc[i][j]);
        }
        if (c < 24) commit_chunk((c + 1) & 1);   // vmcnt drain post-compute
    }

    // epilogue: +b1, RoPE, fold 0.125 into qw, emit bf16
    const float4 b1v = *(const float4*)&b1[tc4];
    const float freq = powf(10000.0f, -(float)tc * (1.0f / 32.0f));
#pragma unroll
    for (int i = 0; i < 4; ++i) {
        const int grow = m0 + tr4 + i;
        const float pos = (float)(grow & (S_ - 1));
        float sv, cv;
        sincosf(pos * freq, &sv, &cv);
        const float q0 = acc[i][0] + b1v.x;
        const float k0 = acc[i][1] + b1v.y;
        const float q1 = acc[i][2] + b1v.z;
        const float k1 = acc[i][3] + b1v.w;
        ushort2 qp, kp;
        qp.x = f2bf((q0 * cv - q1 * sv) * 0.125f);
        qp.y = f2bf((q1 * cv + q0 * sv) * 0.125f);
        kp.x = f2bf(k0 * cv - k1 * sv);
        kp.y = f2bf(k1 * cv + k0 * sv);
        *(ushort2*)(qw + (size_t)grow * D_ + 2 * tc) = qp;
        *(ushort2*)(kw + (size_t)grow * D_ + 2 * tc) = kp;
    }
}

// ---------------------------------------------------------------------------
// k1b: bias = (h @ W2 + b2) * 0.5, transposed bias_t[b][c][s]. (unchanged)
// ---------------------------------------------------------------------------
__global__ __launch_bounds__(256) void k1b_bias(
    const float* __restrict__ lhs, const float* __restrict__ hf,
    const float* __restrict__ W2,  const float* __restrict__ b2,
    float* __restrict__ bias_t)
{
    __shared__ float sh_hT[4][32][65];
    __shared__ float red[4][64][19];

    const int tid  = threadIdx.x;
    const int w    = tid >> 6;
    const int lane = tid & 63;
    const int r0   = blockIdx.x << 6;

    const int c0 = (w == 0) ? 0 : 6 * w + 1;
    const int c1 = 6 * w + 7;

    float acc[18];
#pragma unroll
    for (int j = 0; j < 18; ++j) acc[j] = 0.0f;

    for (int c = c0; c < c1; ++c) {
        const int k0 = c << 5;
#pragma unroll
        for (int s = 0; s < 8; ++s) {
            const int flat4 = lane + (s << 6);
            const int row   = flat4 >> 3;
            const int kc4   = (flat4 & 7) << 2;
            const float* src = (k0 < HDIM)
                ? lhs + (size_t)(r0 + row) * HDIM + k0 + kc4
                : hf  + (size_t)(r0 + row) * FDIM + (k0 - HDIM) + kc4;
            const float4 v = *(const float4*)src;
            sh_hT[w][kc4 + 0][row] = v.x;
            sh_hT[w][kc4 + 1][row] = v.y;
            sh_hT[w][kc4 + 2][row] = v.z;
            sh_hT[w][kc4 + 3][row] = v.w;
        }
#pragma unroll 4
        for (int kk = 0; kk < 32; ++kk) {
            const float hv = sh_hT[w][kk][lane];
            const float* w2r = W2 + (size_t)(k0 + kk) * 18;
#pragma unroll
            for (int j = 0; j < 18; ++j)
                acc[j] = fmaf(hv, w2r[j], acc[j]);
        }
    }

#pragma unroll
    for (int j = 0; j < 18; ++j) red[w][lane][j] = acc[j];
    __syncthreads();

    if (w == 0) {
        const int b = r0 >> 10;
        const int s = r0 & (S_ - 1);
#pragma unroll
        for (int j = 0; j < 18; ++j) {
            float v = red[0][lane][j] + red[1][lane][j] +
                      red[2][lane][j] + red[3][lane][j];
            v = (v + b2[j]) * 0.5f;
            bias_t[(((size_t)(b * 18 + j)) << 10) + s + lane] = v;
        }
    }
}

// ---------------------------------------------------------------------------
// k2: 64x64 (m,n) tile per block. QK^T via mfma_f32_16x16x32_bf16 from
// XOR-swizzled LDS; epilogue fuses bias + mask + tril into one fma/elem.
// ---------------------------------------------------------------------------
__global__ __launch_bounds__(256) void k2_logits(
    const unsigned short* __restrict__ qw, const unsigned short* __restrict__ kw,
    const float* __restrict__ bias_t, const int* __restrict__ mask,
    float* __restrict__ out)
{
    __shared__ unsigned short qsm[64 * 64];   // [row][k] bf16, slot-swizzled
    __shared__ unsigned short ksm[64 * 64];
    __shared__ float bn[18][64];
    __shared__ float bm[18][64];
    __shared__ float mqf[64], mkf[64];

    const int tid = threadIdx.x;
    // XCD-chunked swizzle: XCD x gets tiles [x*256, (x+1)*256) = batch x
    int bid;
    {
        const int i = blockIdx.x;
        bid = (i & 7) * 256 + (i >> 3);
    }
    const int b   = bid >> 8;
    const int rem = bid & 255;
    const int m0  = (rem >> 4) << 6;
    const int n0  = (rem & 15) << 6;

    // stage qw/kw tiles (bf16, 16B chunks, XOR slot swizzle)
#pragma unroll
    for (int u = 0; u < 2; ++u) {
        const int idx = tid + (u << 8);      // 0..511
        const int row = idx >> 3;
        const int c8  = idx & 7;
        const int sb  = (row << 7) + ((c8 ^ (row & 7)) << 4);
        const uint4 vq = *(const uint4*)(qw + ((size_t)(b << 10) + m0 + row) * D_ + (c8 << 3));
        *(uint4*)((char*)qsm + sb) = vq;
        const uint4 vk = *(const uint4*)(kw + ((size_t)(b << 10) + n0 + row) * D_ + (c8 << 3));
        *(uint4*)((char*)ksm + sb) = vk;
    }
    for (int idx = tid; idx < 18 * 64; idx += 256) {
        const int c = idx >> 6;
        const int x = idx & 63;
        bn[c][x] = bias_t[(((size_t)(b * 18 + c)) << 10) + n0 + x];
        bm[c][x] = bias_t[(((size_t)(b * 18 + c)) << 10) + m0 + x];
    }
    if (tid < 64)        mqf[tid]      = (float)mask[b * S_ + m0 + tid];
    else if (tid < 128)  mkf[tid - 64] = (float)mask[b * S_ + n0 + (tid - 64)];
    __syncthreads();

    const int lane = tid & 63;
    const int w    = tid >> 6;
    const int wr   = w >> 1;           // m half
    const int wc   = w & 1;            // n half
    const int r16  = lane & 15;
    const int g    = lane >> 4;

    f32x4 acc[2][2];
    const f32x4 zero = {0.0f, 0.0f, 0.0f, 0.0f};
#pragma unroll
    for (int mi = 0; mi < 2; ++mi)
#pragma unroll
        for (int ni = 0; ni < 2; ++ni) acc[mi][ni] = zero;

#pragma unroll
    for (int ku = 0; ku < 2; ++ku) {
        short8 af[2], bf[2];
#pragma unroll
        for (int mi = 0; mi < 2; ++mi) {
            const int row  = wr * 32 + mi * 16 + r16;
            const int slot = ((ku << 2) + g) ^ (row & 7);
            af[mi] = *(const short8*)((const char*)qsm + (row << 7) + (slot << 4));
        }
#pragma unroll
        for (int ni = 0; ni < 2; ++ni) {
            const int row  = wc * 32 + ni * 16 + r16;
            const int slot = ((ku << 2) + g) ^ (row & 7);
            bf[ni] = *(const short8*)((const char*)ksm + (row << 7) + (slot << 4));
        }
#pragma unroll
        for (int mi = 0; mi < 2; ++mi)
#pragma unroll
            for (int ni = 0; ni < 2; ++ni)
                acc[mi][ni] = __builtin_amdgcn_mfma_f32_16x16x32_bf16(
                    af[mi], bf[ni], acc[mi][ni], 0, 0, 0);
    }

    // per-lane mask/tril folding: v = (acc + bn + bm) * p + ad
    float p[2][2][4], ad[2][2][4];
    int   moff[2][4];
    int   noff[2];
#pragma unroll
    for (int ni = 0; ni < 2; ++ni) noff[ni] = n0 + wc * 32 + ni * 16 + r16;
#pragma unroll
    for (int mi = 0; mi < 2; ++mi) {
#pragma unroll
        for (int rr = 0; rr < 4; ++rr) {
            const int mrow = wr * 32 + mi * 16 + g * 4 + rr;
            const int mg   = m0 + mrow;
            moff[mi][rr] = mg << 10;
            const float fm = mqf[mrow];
#pragma unroll
            for (int ni = 0; ni < 2; ++ni) {
                const float fk = mkf[wc * 32 + ni * 16 + r16];
                p[mi][ni][rr]  = fm * fk;
                float a = NEGV * ((1.0f - fm) * fk + (1.0f - fk));
                if (mg > noff[ni]) a += NEGV;
                ad[mi][ni][rr] = a;
            }
        }
    }

    const size_t obase = ((size_t)(b * 9)) << 20;
#pragma unroll
    for (int t = 0; t < 9; ++t) {
        const size_t tb = obase + ((size_t)t << 20);
        float bnv[2];
#pragma unroll
        for (int ni = 0; ni < 2; ++ni) bnv[ni] = bn[2 * t][wc * 32 + ni * 16 + r16];
#pragma unroll
        for (int mi = 0; mi < 2; ++mi) {
            const f32x4 bmv = *(const f32x4*)&bm[2 * t + 1][wr * 32 + mi * 16 + g * 4];
#pragma unroll
            for (int rr = 0; rr < 4; ++rr) {
#pragma unroll
                for (int ni = 0; ni < 2; ++ni) {
                    const float v = fmaf(acc[mi][ni][rr] + bnv[ni] + bmv[rr],
                                         p[mi][ni][rr], ad[mi][ni][rr]);
                    out[tb + (size_t)(moff[mi][rr] + noff[ni])] = v;
                }
            }
        }
    }
}

extern "C" void kernel_launch(void* const* d_in, const int* in_sizes, int n_in,
                              void* d_out, int out_size, void* d_ws, size_t ws_size,
                              hipStream_t stream) {
    const float* lhs  = (const float*)d_in[0];
    const float* hf   = (const float*)d_in[1];
    const int*   mask = (const int*)  d_in[2];
    const float* W1   = (const float*)d_in[3];
    const float* b1   = (const float*)d_in[4];
    const float* W2   = (const float*)d_in[5];
    const float* b2   = (const float*)d_in[6];
    float* out = (float*)d_out;

    unsigned short* qw = (unsigned short*)d_ws;              // 1 MB
    unsigned short* kw = qw + (size_t)B_ * S_ * D_;          // 1 MB
    float* bias_t = (float*)((char*)d_ws + (4u << 20));      // at 4 MB

    k1_proj<<<(B_ * S_) / 32, 256, 0, stream>>>(lhs, hf, W1, b1, qw, kw);
    k1b_bias<<<(B_ * S_) / 64, 256, 0, stream>>>(lhs, hf, W2, b2, bias_t);
    k2_logits<<<B_ * 16 * 16, 256, 0, stream>>>(qw, kw, bias_t, mask, out);
}

// Round 4
// 125.520 us; speedup vs baseline: 3.0268x; 1.2998x over previous
//
#include <hip/hip_runtime.h>
#include <math.h>

#define B_   8
#define S_   1024
#define HDIM 768
#define FDIM 32
#define KDIM 800
#define D_   64
#define NT_  12        // k1 n-tiles: 4 q + 4 k + 2 bias + 2 pad (192 cols)
#define KSTEPS 25

constexpr float NEGV = -1000000000000.0f;

typedef __attribute__((ext_vector_type(8))) short short8;
typedef __attribute__((ext_vector_type(4))) float f32x4;

static __device__ __forceinline__ unsigned short f2bf(float f) {
    unsigned int x = __float_as_uint(f);
    unsigned int r = (x + 0x7fffu + ((x >> 16) & 1u)) >> 16;   // RNE
    return (unsigned short)r;
}
static __device__ __forceinline__ unsigned int pack2(float a, float b) {
    return (unsigned int)f2bf(a) | ((unsigned int)f2bf(b) << 16);
}

// ---------------------------------------------------------------------------
// k0: repack W1/W2 (f32, col-interleaved) -> Wt bf16 in MFMA-frag chunk order:
// Wt[step][chunk i]: i = tile*64 + g*16 + col; chunk = 8 bf16 of
// (k = step*32 + g*8 .. +7) for output column nc = tile*16+col.
// Column order nc: 0..63 = q cols (W1 col 2j), 64..127 = k cols (W1 2j+1),
// 128..145 = W2 cols, 146..191 = zero pad. Also bv[192] = reordered b1/b2.
// ---------------------------------------------------------------------------
__global__ __launch_bounds__(256) void k0_prep(
    const float* __restrict__ W1, const float* __restrict__ b1,
    const float* __restrict__ W2, const float* __restrict__ b2,
    unsigned short* __restrict__ Wt, float* __restrict__ bv)
{
    __shared__ float shW[32][136];
    __shared__ float shW2[32][20];
    const int tid = threadIdx.x;
    const int k0 = blockIdx.x << 5;
#pragma unroll
    for (int p = 0; p < 4; ++p) {
        const int flat = tid + (p << 8);
        const int kk = flat >> 5;
        const int c4 = (flat & 31) << 2;
        const float4 v = *(const float4*)(W1 + (size_t)(k0 + kk) * 128 + c4);
        shW[kk][c4 + 0] = v.x; shW[kk][c4 + 1] = v.y;
        shW[kk][c4 + 2] = v.z; shW[kk][c4 + 3] = v.w;
    }
    for (int i = tid; i < 576; i += 256)
        shW2[i / 18][i % 18] = W2[(size_t)k0 * 18 + i];
    __syncthreads();

    for (int i = tid; i < 768; i += 256) {
        const int tile = i >> 6, g = (i >> 4) & 3, col = i & 15;
        const int nc = tile * 16 + col;
        unsigned int pk[4];
#pragma unroll
        for (int h = 0; h < 4; ++h) {
            const int ka = g * 8 + 2 * h, kb = ka + 1;
            float a, b;
            if (nc < 64)       { a = shW[ka][2*nc];          b = shW[kb][2*nc]; }
            else if (nc < 128) { a = shW[ka][2*(nc-64)+1];   b = shW[kb][2*(nc-64)+1]; }
            else if (nc < 146) { a = shW2[ka][nc-128];       b = shW2[kb][nc-128]; }
            else               { a = 0.0f; b = 0.0f; }
            pk[h] = pack2(a, b);
        }
        *(uint4*)(Wt + ((size_t)blockIdx.x * 768 + i) * 8) =
            make_uint4(pk[0], pk[1], pk[2], pk[3]);
    }
    if (blockIdx.x == 0 && tid < 192) {
        float v = tid < 64  ? b1[2 * tid]
                : tid < 128 ? b1[2 * (tid - 64) + 1]
                : tid < 146 ? b2[tid - 128] : 0.0f;
        bv[tid] = v;
    }
}

// ---------------------------------------------------------------------------
// k1: fused h@[W1|W2] via MFMA (bf16), + b, + RoPE, -> qw/kw bf16 + bias_t.
// BM=16 rows, 192 cols (12 tiles), 4 waves x 3 tiles, 25 K-steps of 32.
// LDS chunks in frag order: reads identity (bank-floor), staging coalesced.
// ---------------------------------------------------------------------------
__global__ __launch_bounds__(256) void k1_proj(
    const float* __restrict__ lhs, const float* __restrict__ hf,
    const unsigned short* __restrict__ Wt, const float* __restrict__ bv,
    unsigned short* __restrict__ qw, unsigned short* __restrict__ kw,
    float* __restrict__ bias_t)
{
    __shared__ __align__(16) unsigned short st[2][832 * 8];  // 64 A + 768 B chunks
    __shared__ __align__(16) unsigned short repack[16][128];

    const int tid  = threadIdx.x;
    const int m0   = blockIdx.x << 4;
    const int lane = tid & 63;
    const int w    = tid >> 6;
    const int r16  = lane & 15;
    const int g    = lane >> 4;

    // A staging: tid<128: (row, k-quad) -> chunk g*16+row, half
    const int arow   = tid >> 3;
    const int akq    = (tid & 7) << 2;
    const int achunk = ((akq >> 3) << 4) + arow;
    const int ahalf  = (akq >> 2) & 1;

    float4 rA;
    uint4  rB[3];

    auto loadA = [&](int c) {
        if (tid < 128) {
            const int k = (c << 5) + akq;
            rA = (k < HDIM)
               ? *(const float4*)(lhs + (size_t)(m0 + arow) * HDIM + k)
               : *(const float4*)(hf  + (size_t)(m0 + arow) * FDIM + (k - HDIM));
        }
    };
    auto loadB = [&](int c) {
#pragma unroll
        for (int u = 0; u < 3; ++u) {
            const int i = tid + (u << 8);
            rB[u] = *(const uint4*)(Wt + ((size_t)c * 768 + i) * 8);
        }
    };
    auto commit = [&](int buf) {
        if (tid < 128)
            *(uint2*)&st[buf][achunk * 8 + ahalf * 4] =
                make_uint2(pack2(rA.x, rA.y), pack2(rA.z, rA.w));
#pragma unroll
        for (int u = 0; u < 3; ++u) {
            const int i = tid + (u << 8);
            *(uint4*)&st[buf][(64 + i) * 8] = rB[u];
        }
    };

    f32x4 acc[3];
    const f32x4 zero = {0.0f, 0.0f, 0.0f, 0.0f};
#pragma unroll
    for (int u = 0; u < 3; ++u) acc[u] = zero;

    loadA(0); loadB(0); commit(0);

    for (int c = 0; c < KSTEPS; ++c) {
        __syncthreads();                       // buf[c&1] committed
        if (c + 1 < KSTEPS) { loadA(c + 1); loadB(c + 1); }
        const int buf = c & 1;
        const short8 af = *(const short8*)&st[buf][(g * 16 + r16) * 8];
#pragma unroll
        for (int u = 0; u < 3; ++u) {
            const int tile = w * 3 + u;
            const short8 bf =
                *(const short8*)&st[buf][(64 + tile * 64 + g * 16 + r16) * 8];
            acc[u] = __builtin_amdgcn_mfma_f32_16x16x32_bf16(af, bf, acc[u], 0, 0, 0);
        }
        __syncthreads();                       // reads of other buffer done
        if (c + 1 < KSTEPS) commit((c + 1) & 1);
    }

    // epilogue: C rows = g*4+rr (16 rows), col = lane&15 within tile
    const int bidx = m0 >> 10;
    const int s0   = m0 & (S_ - 1);
#pragma unroll
    for (int u = 0; u < 3; ++u) {
        const int tile = w * 3 + u;
        if (tile < 8) {                         // q (0-3) / k (4-7) with RoPE
            const int jj   = (tile < 4 ? tile : tile - 4) * 16 + r16;   // 0..63
            const float bvv  = bv[tile * 16 + r16];
            const float freq = exp2f((float)(jj >> 1) * -0.4152410119f);
            const float sgn  = (jj & 1) ? 1.0f : -1.0f;
            const float scl  = (tile < 4) ? 0.125f : 1.0f;
            float x[4], p[4];
#pragma unroll
            for (int rr = 0; rr < 4; ++rr) x[rr] = acc[u][rr] + bvv;
#pragma unroll
            for (int rr = 0; rr < 4; ++rr) p[rr] = __shfl_xor(x[rr], 1, 64);
            const int cbase = (tile < 4 ? 0 : 64) + jj;
#pragma unroll
            for (int rr = 0; rr < 4; ++rr) {
                const float pos = (float)(s0 + g * 4 + rr);
                float sv, cv;
                sincosf(pos * freq, &sv, &cv);
                repack[g * 4 + rr][cbase] =
                    f2bf(fmaf(p[rr], sgn * sv, x[rr] * cv) * scl);
            }
        } else if (tile < 10) {                 // bias cols
            const int cc = (tile - 8) * 16 + r16;
            if (cc < 18) {
                const float bvv = bv[tile * 16 + r16];
                f32x4 v;
#pragma unroll
                for (int rr = 0; rr < 4; ++rr) v[rr] = (acc[u][rr] + bvv) * 0.5f;
                *(f32x4*)(bias_t + (((size_t)(bidx * 18 + cc)) << 10) + s0 + g * 4) = v;
            }
        }
    }
    __syncthreads();
    {
        const int row = tid >> 4, seg = tid & 15;
        const uint4 v = *(const uint4*)&repack[row][seg * 8];
        if (seg < 8) *(uint4*)(qw + ((size_t)(m0 + row)) * D_ + seg * 8) = v;
        else         *(uint4*)(kw + ((size_t)(m0 + row)) * D_ + (seg - 8) * 8) = v;
    }
}

// ---------------------------------------------------------------------------
// k2: 64x64 (m,n) tile per block. QK^T via mfma_f32_16x16x32_bf16 from
// XOR-swizzled LDS; epilogue fuses bias + mask + tril.  (unchanged from R3)
// ---------------------------------------------------------------------------
__global__ __launch_bounds__(256) void k2_logits(
    const unsigned short* __restrict__ qw, const unsigned short* __restrict__ kw,
    const float* __restrict__ bias_t, const int* __restrict__ mask,
    float* __restrict__ out)
{
    __shared__ unsigned short qsm[64 * 64];
    __shared__ unsigned short ksm[64 * 64];
    __shared__ float bn[18][64];
    __shared__ float bm[18][64];
    __shared__ float mqf[64], mkf[64];

    const int tid = threadIdx.x;
    int bid;
    {
        const int i = blockIdx.x;
        bid = (i & 7) * 256 + (i >> 3);    // XCD-chunked: XCD x -> batch x
    }
    const int b   = bid >> 8;
    const int rem = bid & 255;
    const int m0  = (rem >> 4) << 6;
    const int n0  = (rem & 15) << 6;

#pragma unroll
    for (int u = 0; u < 2; ++u) {
        const int idx = tid + (u << 8);
        const int row = idx >> 3;
        const int c8  = idx & 7;
        const int sb  = (row << 7) + ((c8 ^ (row & 7)) << 4);
        const uint4 vq = *(const uint4*)(qw + ((size_t)(b << 10) + m0 + row) * D_ + (c8 << 3));
        *(uint4*)((char*)qsm + sb) = vq;
        const uint4 vk = *(const uint4*)(kw + ((size_t)(b << 10) + n0 + row) * D_ + (c8 << 3));
        *(uint4*)((char*)ksm + sb) = vk;
    }
    for (int idx = tid; idx < 18 * 64; idx += 256) {
        const int c = idx >> 6;
        const int x = idx & 63;
        bn[c][x] = bias_t[(((size_t)(b * 18 + c)) << 10) + n0 + x];
        bm[c][x] = bias_t[(((size_t)(b * 18 + c)) << 10) + m0 + x];
    }
    if (tid < 64)        mqf[tid]      = (float)mask[b * S_ + m0 + tid];
    else if (tid < 128)  mkf[tid - 64] = (float)mask[b * S_ + n0 + (tid - 64)];
    __syncthreads();

    const int lane = tid & 63;
    const int w    = tid >> 6;
    const int wr   = w >> 1;
    const int wc   = w & 1;
    const int r16  = lane & 15;
    const int g    = lane >> 4;

    f32x4 acc[2][2];
    const f32x4 zero = {0.0f, 0.0f, 0.0f, 0.0f};
#pragma unroll
    for (int mi = 0; mi < 2; ++mi)
#pragma unroll
        for (int ni = 0; ni < 2; ++ni) acc[mi][ni] = zero;

#pragma unroll
    for (int ku = 0; ku < 2; ++ku) {
        short8 af[2], bf[2];
#pragma unroll
        for (int mi = 0; mi < 2; ++mi) {
            const int row  = wr * 32 + mi * 16 + r16;
            const int slot = ((ku << 2) + g) ^ (row & 7);
            af[mi] = *(const short8*)((const char*)qsm + (row << 7) + (slot << 4));
        }
#pragma unroll
        for (int ni = 0; ni < 2; ++ni) {
            const int row  = wc * 32 + ni * 16 + r16;
            const int slot = ((ku << 2) + g) ^ (row & 7);
            bf[ni] = *(const short8*)((const char*)ksm + (row << 7) + (slot << 4));
        }
#pragma unroll
        for (int mi = 0; mi < 2; ++mi)
#pragma unroll
            for (int ni = 0; ni < 2; ++ni)
                acc[mi][ni] = __builtin_amdgcn_mfma_f32_16x16x32_bf16(
                    af[mi], bf[ni], acc[mi][ni], 0, 0, 0);
    }

    float p[2][2][4], ad[2][2][4];
    int   moff[2][4];
    int   noff[2];
#pragma unroll
    for (int ni = 0; ni < 2; ++ni) noff[ni] = n0 + wc * 32 + ni * 16 + r16;
#pragma unroll
    for (int mi = 0; mi < 2; ++mi) {
#pragma unroll
        for (int rr = 0; rr < 4; ++rr) {
            const int mrow = wr * 32 + mi * 16 + g * 4 + rr;
            const int mg   = m0 + mrow;
            moff[mi][rr] = mg << 10;
            const float fm = mqf[mrow];
#pragma unroll
            for (int ni = 0; ni < 2; ++ni) {
                const float fk = mkf[wc * 32 + ni * 16 + r16];
                p[mi][ni][rr]  = fm * fk;
                float a = NEGV * ((1.0f - fm) * fk + (1.0f - fk));
                if (mg > noff[ni]) a += NEGV;
                ad[mi][ni][rr] = a;
            }
        }
    }

    const size_t obase = ((size_t)(b * 9)) << 20;
#pragma unroll
    for (int t = 0; t < 9; ++t) {
        const size_t tb = obase + ((size_t)t << 20);
        float bnv[2];
#pragma unroll
        for (int ni = 0; ni < 2; ++ni) bnv[ni] = bn[2 * t][wc * 32 + ni * 16 + r16];
#pragma unroll
        for (int mi = 0; mi < 2; ++mi) {
            const f32x4 bmv = *(const f32x4*)&bm[2 * t + 1][wr * 32 + mi * 16 + g * 4];
#pragma unroll
            for (int rr = 0; rr < 4; ++rr) {
#pragma unroll
                for (int ni = 0; ni < 2; ++ni) {
                    const float v = fmaf(acc[mi][ni][rr] + bnv[ni] + bmv[rr],
                                         p[mi][ni][rr], ad[mi][ni][rr]);
                    out[tb + (size_t)(moff[mi][rr] + noff[ni])] = v;
                }
            }
        }
    }
}

extern "C" void kernel_launch(void* const* d_in, const int* in_sizes, int n_in,
                              void* d_out, int out_size, void* d_ws, size_t ws_size,
                              hipStream_t stream) {
    const float* lhs  = (const float*)d_in[0];
    const float* hf   = (const float*)d_in[1];
    const int*   mask = (const int*)  d_in[2];
    const float* W1   = (const float*)d_in[3];
    const float* b1   = (const float*)d_in[4];
    const float* W2   = (const float*)d_in[5];
    const float* b2   = (const float*)d_in[6];
    float* out = (float*)d_out;

    unsigned short* qw = (unsigned short*)d_ws;              // 1 MB
    unsigned short* kw = qw + (size_t)B_ * S_ * D_;          // 1 MB
    float* bias_t = (float*)((char*)d_ws + (4u << 20));      // 576 KB @ 4 MB
    unsigned short* Wt = (unsigned short*)((char*)d_ws + (8u << 20)); // 300 KB @ 8 MB
    float* bv = (float*)((char*)d_ws + (9u << 20));          // 768 B @ 9 MB

    k0_prep<<<KSTEPS, 256, 0, stream>>>(W1, b1, W2, b2, Wt, bv);
    k1_proj<<<(B_ * S_) / 16, 256, 0, stream>>>(lhs, hf, Wt, bv, qw, kw, bias_t);
    k2_logits<<<B_ * 16 * 16, 256, 0, stream>>>(qw, kw, bias_t, mask, out);
}